// Round 9
// baseline (353.096 us; speedup 1.0000x reference)
//
#include <hip/hip_runtime.h>
#include <hip/hip_bf16.h>
#include <math.h>

#define B_ 4
#define N_ 4096
#define M_ 1024
#define C_ 384
#define NH_ 8
#define HD_ 48

typedef float f32x4 __attribute__((ext_vector_type(4)));
typedef float f32x16 __attribute__((ext_vector_type(16)));
typedef short bf16x8 __attribute__((ext_vector_type(8)));

typedef __attribute__((address_space(3))) unsigned int lds_uint;
typedef const __attribute__((address_space(1))) unsigned int glob_uint;

__device__ __forceinline__ void gld_lds16(const void* g, void* l) {
    // async global->LDS, 16 B/lane; LDS dest = wave-uniform base + lane*16
    __builtin_amdgcn_global_load_lds((glob_uint*)g, (lds_uint*)l, 16, 0, 0);
}

__device__ __forceinline__ unsigned short f2bf(float x) {  // RNE
    unsigned int u = __builtin_bit_cast(unsigned int, x);
    return (unsigned short)((u + 0x7FFFu + ((u >> 16) & 1u)) >> 16);
}
__device__ __forceinline__ float bf2f(unsigned short x) {
    return __builtin_bit_cast(float, (unsigned int)x << 16);
}
__device__ __forceinline__ float fast_exp2(float x) {
#if __has_builtin(__builtin_amdgcn_exp2f)
    return __builtin_amdgcn_exp2f(x);
#else
    return exp2f(x);
#endif
}
__device__ __forceinline__ uint2 pack4_rne(float a, float b, float c, float d) {
    uint2 r;
    r.x = (unsigned int)f2bf(a) | ((unsigned int)f2bf(b) << 16);
    r.y = (unsigned int)f2bf(c) | ((unsigned int)f2bf(d) << 16);
    return r;
}

// 48^-0.5 * log2(e): softmax via 2^x
#define QSCALE 0.20823490983597203f
#define INV_QSCALE (1.0f / 0.20823490983597203f)

// ---------------------------------------------------------------------------
// Fused prep: blocks [0,7680) convert activations fp32->bf16 (flat float4
// grid; q_x then kv_x); blocks [7680,7824) transpose+convert weights.
// ---------------------------------------------------------------------------
__global__ __launch_bounds__(256)
void prep(const float* __restrict__ qx_f, unsigned short* __restrict__ qx_bf,
          const float* __restrict__ kvx_f, unsigned short* __restrict__ kvx_bf,
          const float* __restrict__ Wq, const float* __restrict__ Wkv,
          const float* __restrict__ Wproj,
          unsigned short* __restrict__ Wq_t, unsigned short* __restrict__ Wkv_t,
          unsigned short* __restrict__ Wproj_t)
{
    __shared__ unsigned short T[64 * 72];
    const int tid = threadIdx.x;
    int bid = blockIdx.x;

    if (bid < 7680) {
        size_t i4 = (size_t)bid * 256 + tid;
        const float* src; unsigned short* dst;
        if (i4 < 1572864u) { src = qx_f; dst = qx_bf; }
        else { src = kvx_f; dst = kvx_bf; i4 -= 1572864u; }
        float4 v = *(const float4*)&src[i4 * 4];
        *(uint2*)&dst[i4 * 4] = pack4_rne(v.x, v.y, v.z, v.w);
        return;
    }

    bid -= 7680;
    const float* W; unsigned short* Wt; int N, kt, nt;
    if (bid < 36)       { W = Wq;    Wt = Wq_t;    N = 384; kt = bid / 6;  nt = bid - kt * 6; }
    else if (bid < 108) { bid -= 36;  W = Wkv;   Wt = Wkv_t;   N = 768; kt = bid / 12; nt = bid - kt * 12; }
    else                { bid -= 108; W = Wproj; Wt = Wproj_t; N = 384; kt = bid / 6;  nt = bid - kt * 6; }
    const int k0 = kt * 64, n0 = nt * 64;

    #pragma unroll
    for (int it = 0; it < 4; ++it) {
        int k = it * 16 + (tid >> 4);
        int n4 = (tid & 15) * 4;
        float4 v = *(const float4*)&W[(size_t)(k0 + k) * N + n0 + n4];
        T[(n4 + 0) * 72 + k] = f2bf(v.x);
        T[(n4 + 1) * 72 + k] = f2bf(v.y);
        T[(n4 + 2) * 72 + k] = f2bf(v.z);
        T[(n4 + 3) * 72 + k] = f2bf(v.w);
    }
    __syncthreads();
    #pragma unroll
    for (int i = 0; i < 2; ++i) {
        int s = tid + 256 * i;
        int n = s >> 3, part = s & 7;
        *(uint4*)&Wt[(size_t)(n0 + n) * C_ + k0 + part * 8] = *(const uint4*)&T[n * 72 + part * 8];
    }
}

// ---------------------------------------------------------------------------
// m97-style GEMM core: 128x128 tile, BK=64, global_load_lds staging with
// XOR-8 chunk swizzle (conflict-free ds_read_b128, no padding needed).
// Single-buffered (R6 version; R8's double-buffer measured neutral).
// ---------------------------------------------------------------------------
__device__ __forceinline__ void stage128(const unsigned short* src, unsigned short* lds,
                                         int kk, int tid) {
    #pragma unroll
    for (int r = 0; r < 4; ++r) {
        int off = r * 256 + tid;          // 16B-slot index 0..1023
        int row = off >> 3;
        int c = off & 7;
        int gc = c ^ (row & 7);
        gld_lds16(src + (size_t)row * C_ + kk + gc * 8, lds + (size_t)off * 8);
    }
}
__device__ __forceinline__ bf16x8 frag_ld(const unsigned short* lds, int row, int chunk) {
    return *(const bf16x8*)&lds[row * 64 + ((chunk ^ (row & 7)) << 3)];
}

#define GEMM_CORE(Aptr, Wptr)                                                        \
    f32x4 acc[4][4];                                                                 \
    _Pragma("unroll")                                                                \
    for (int rt = 0; rt < 4; ++rt)                                                   \
        _Pragma("unroll")                                                            \
        for (int ct = 0; ct < 4; ++ct) acc[rt][ct] = (f32x4){0.f, 0.f, 0.f, 0.f};    \
    const int wrow0 = (wave & 1) * 64;                                               \
    const int wcol0 = (wave >> 1) * 64;                                              \
    for (int kk = 0; kk < C_; kk += 64) {                                            \
        __syncthreads();                                                             \
        stage128(Aptr, As, kk, tid);                                                 \
        stage128(Wptr, Ws, kk, tid);                                                 \
        __syncthreads();                                                             \
        _Pragma("unroll")                                                            \
        for (int ks = 0; ks < 2; ++ks) {                                             \
            bf16x8 af[4], wf[4];                                                     \
            _Pragma("unroll")                                                        \
            for (int rt = 0; rt < 4; ++rt)                                           \
                af[rt] = frag_ld(As, wrow0 + rt * 16 + ln, ks * 4 + quad);           \
            _Pragma("unroll")                                                        \
            for (int ct = 0; ct < 4; ++ct)                                           \
                wf[ct] = frag_ld(Ws, wcol0 + ct * 16 + ln, ks * 4 + quad);           \
            _Pragma("unroll")                                                        \
            for (int rt = 0; rt < 4; ++rt)                                           \
                _Pragma("unroll")                                                    \
                for (int ct = 0; ct < 4; ++ct)                                       \
                    acc[rt][ct] = __builtin_amdgcn_mfma_f32_16x16x32_bf16(           \
                        wf[ct], af[rt], acc[rt][ct], 0, 0, 0);                       \
        }                                                                            \
    }

// ---------------------------------------------------------------------------
// Fused q-proj (blocks [0,384)) + kv-proj (blocks [384,576)).
// ---------------------------------------------------------------------------
__global__ __launch_bounds__(256)
void gemm_qkv(const unsigned short* __restrict__ qx, const unsigned short* __restrict__ kvx,
              const unsigned short* __restrict__ Wqt, const unsigned short* __restrict__ Wkvt,
              unsigned short* __restrict__ qbf,
              unsigned short* __restrict__ kbf, unsigned short* __restrict__ vbf)
{
    __shared__ unsigned short As[128 * 64];
    __shared__ unsigned short Ws[128 * 64];
    const int tid = threadIdx.x;
    const int wave = tid >> 6;
    const int lane = tid & 63;
    const int ln = lane & 15;
    const int quad = lane >> 4;

    int bid = blockIdx.x;
    int mode, row0, col0;
    const unsigned short *A, *Wt;
    if (bid < 384) { mode = 0; A = qx;  Wt = Wqt;  row0 = (bid / 3) * 128; col0 = (bid % 3) * 128; }
    else { bid -= 384; mode = 1; A = kvx; Wt = Wkvt; row0 = (bid / 6) * 128; col0 = (bid % 6) * 128; }

    GEMM_CORE(A + (size_t)row0 * C_, Wt + (size_t)col0 * C_)

    #pragma unroll
    for (int rt = 0; rt < 4; ++rt) {
        int grow = row0 + wrow0 + rt * 16 + ln;
        #pragma unroll
        for (int ct = 0; ct < 4; ++ct) {
            int col = col0 + wcol0 + ct * 16 + quad * 4;
            f32x4 v = acc[rt][ct];
            if (mode == 0) {
                int b = grow >> 12, n = grow & (N_ - 1);
                int h = col / HD_, d = col - h * HD_;
                *(uint2*)&qbf[(((size_t)(b * NH_ + h) * N_) + n) * HD_ + d] =
                    pack4_rne(v[0] * QSCALE, v[1] * QSCALE, v[2] * QSCALE, v[3] * QSCALE);
            } else {
                int b = grow >> 10, m = grow & (M_ - 1);
                if (col < C_) {
                    int h = col / HD_, d = col - h * HD_;
                    *(uint2*)&kbf[(((size_t)(b * NH_ + h) * M_) + m) * HD_ + d] =
                        pack4_rne(v[0], v[1], v[2], v[3]);
                } else {
                    int c2 = col - C_;
                    int h = c2 / HD_, d = c2 - h * HD_;
                    size_t base = ((size_t)(b * NH_ + h) * HD_ + d) * M_ + m;
                    #pragma unroll
                    for (int r = 0; r < 4; ++r) vbf[base + (size_t)r * M_] = f2bf(v[r]);
                }
            }
        }
    }
}

// ---------------------------------------------------------------------------
// Out-proj: out = q_residual + of @ Wproj + bias. 384 blocks.
// Residual is reconstructed from qbf (scaled q) via 1/QSCALE — no qres buffer.
// ---------------------------------------------------------------------------
__global__ __launch_bounds__(256)
void gemm_out(const unsigned short* __restrict__ A, const unsigned short* __restrict__ Wt,
              float* __restrict__ out0,
              const unsigned short* __restrict__ qbf, const float* __restrict__ bias)
{
    __shared__ unsigned short As[128 * 64];
    __shared__ unsigned short Ws[128 * 64];
    const int tid = threadIdx.x;
    const int wave = tid >> 6;
    const int lane = tid & 63;
    const int ln = lane & 15;
    const int quad = lane >> 4;
    const int row0 = (blockIdx.x / 3) * 128;
    const int col0 = (blockIdx.x % 3) * 128;

    GEMM_CORE(A + (size_t)row0 * C_, Wt + (size_t)col0 * C_)

    #pragma unroll
    for (int rt = 0; rt < 4; ++rt) {
        int grow = row0 + wrow0 + rt * 16 + ln;
        #pragma unroll
        for (int ct = 0; ct < 4; ++ct) {
            int col = col0 + wcol0 + ct * 16 + quad * 4;
            f32x4 v = acc[rt][ct];
            size_t idx = (size_t)grow * C_ + col;
            int b = grow >> 12, n = grow & (N_ - 1);
            int h = col / HD_, d = col - h * HD_;
            uint2 ad = *(const uint2*)&qbf[(((size_t)(b * NH_ + h) * N_) + n) * HD_ + d];
            float4 bi = *(const float4*)&bias[col];
            float4 o;
            o.x = v[0] + bf2f((unsigned short)(ad.x & 0xFFFF)) * INV_QSCALE + bi.x;
            o.y = v[1] + bf2f((unsigned short)(ad.x >> 16))    * INV_QSCALE + bi.y;
            o.z = v[2] + bf2f((unsigned short)(ad.y & 0xFFFF)) * INV_QSCALE + bi.z;
            o.w = v[3] + bf2f((unsigned short)(ad.y >> 16))    * INV_QSCALE + bi.w;
            *(float4*)&out0[idx] = o;
        }
    }
}

// ---------------------------------------------------------------------------
// MFMA attention R16: R12's 32x32x16 in-register-softmax body, M-SPLIT wave
// pairs. Wave w: qpair = w>>1 (64 q-rows at n0w), mhalf = w&1 (mtt range
// [mhalf*16, mhalf*16+16)). Halving the M-range halves K/V loads and MFMA
// equally (amortization ratio preserved — R1's q-split mistake avoided) and
// keeps the qt=2 ILP chains (R13's mistake avoided). Register state is
// unchanged vs R12 (84 VGPR < 128 cap, so launch_bounds(256,4) cannot spill
// — R2/R4's mistake avoided). Grid (32,16)x2 launches = 1024 blocks ->
// 4 blocks/CU = 4 waves/SIMD (2x R12's TLP).
// Combine (exp2-no-max softmax => pure addition): mhalf=1 waves export
// O (64 f32) + rs (2) per lane via 36 KB LDS; mhalf=0 waves add, normalize,
// store. Two __syncthreads total.
// ---------------------------------------------------------------------------
__global__ __launch_bounds__(256, 4)
void attn_mfma(const unsigned short* __restrict__ qbf,
               const unsigned short* __restrict__ kbf,
               const unsigned short* __restrict__ vbf,
               unsigned short* __restrict__ of, int y0)
{
    __shared__ float comb[2][64][72];   // [qpair][lane][72] (stride 72: 16B-aligned, 4-way-max banks)

    const int tid = threadIdx.x;
    const int wave = tid >> 6;
    const int qpair = wave >> 1;
    const int mhalf = wave & 1;
    const int lane = tid & 63;
    const int l31 = lane & 31;
    const int hi  = lane >> 5;       // 0: k 0-7, 1: k 8-15 within a K=16 slice
    const int bh = blockIdx.x;
    const int n0w = (blockIdx.y + y0) * 128 + qpair * 64;

    const unsigned short* kb = kbf + (size_t)bh * M_ * HD_;
    const unsigned short* vb = vbf + (size_t)bh * HD_ * M_;

    // Q B-fragments: qb[qt][s] = Q[q = n0w+qt*32+l31][k = s*16 + hi*8 + 0..7]
    bf16x8 qb[2][3];
    #pragma unroll
    for (int qt = 0; qt < 2; ++qt) {
        const unsigned short* qp = qbf + ((size_t)bh * N_ + n0w + qt * 32 + l31) * HD_;
        #pragma unroll
        for (int s = 0; s < 3; ++s)
            qb[qt][s] = *(const bf16x8*)(qp + s * 16 + hi * 8);
    }

    f32x16 O[2][2];   // [qt][ot2]; rows d = ot2*32 + (reg&3)+8*(reg>>2)+4*hi
    #pragma unroll
    for (int qt = 0; qt < 2; ++qt)
        #pragma unroll
        for (int ot2 = 0; ot2 < 2; ++ot2)
            #pragma unroll
            for (int r = 0; r < 16; ++r) O[qt][ot2][r] = 0.f;
    float rs[2] = {0.f, 0.f};

    const int mtt0 = mhalf * 16;
    for (int mtt = mtt0; mtt < mtt0 + 16; ++mtt) {     // 32 m-rows per iter
        const int m0 = mtt * 32;

        // K A-fragments: ka[s] = K[m = m0+l31][k = s*16 + hi*8 + 0..7]
        bf16x8 ka[3];
        #pragma unroll
        for (int s = 0; s < 3; ++s)
            ka[s] = *(const bf16x8*)&kb[(size_t)(m0 + l31) * HD_ + s * 16 + hi * 8];

        // V A-fragments: va[ot2][s2] = V[d = ot2*32+l31][m = m0 + s2*16 + hi*8 + 0..7]
        // ot2=1 rows 48..63 overread next bh's V / of-region: any bf16 bits ok,
        // they only feed dead acc rows.
        bf16x8 va[2][2];
        #pragma unroll
        for (int ot2 = 0; ot2 < 2; ++ot2)
            #pragma unroll
            for (int s2 = 0; s2 < 2; ++s2)
                va[ot2][s2] = *(const bf16x8*)&vb[(size_t)(ot2 * 32 + l31) * M_ + m0 + s2 * 16 + hi * 8];

        #pragma unroll
        for (int qt = 0; qt < 2; ++qt) {
            f32x16 S;
            #pragma unroll
            for (int r = 0; r < 16; ++r) S[r] = 0.f;
            #pragma unroll
            for (int s = 0; s < 3; ++s)
                S = __builtin_amdgcn_mfma_f32_32x32x16_bf16(ka[s], qb[qt][s], S, 0, 0, 0);

            // lane holds S[m_local = (r&3) + 8*(r>>2) + 4*hi][q = l31]
            float p[16];
            #pragma unroll
            for (int r = 0; r < 16; ++r) p[r] = fast_exp2(S[r]);
            // pairwise sum (short dep chain)
            {
                float s0 = (p[0] + p[1]) + (p[2] + p[3]);
                float s1 = (p[4] + p[5]) + (p[6] + p[7]);
                float s2 = (p[8] + p[9]) + (p[10] + p[11]);
                float s3 = (p[12] + p[13]) + (p[14] + p[15]);
                rs[qt] += (s0 + s1) + (s2 + s3);
            }

            // pack groups g (own m-range 8g+4*hi .. +3):
            // c0[g] = {p[4g], p[4g+1]}, c1[g] = {p[4g+2], p[4g+3]}  (trunc-to-bf16)
            unsigned c0[4], c1[4];
            #pragma unroll
            for (int g = 0; g < 4; ++g) {
                c0[g] = (__builtin_bit_cast(unsigned int, p[4 * g + 0]) >> 16) |
                        (__builtin_bit_cast(unsigned int, p[4 * g + 1]) & 0xFFFF0000u);
                c1[g] = (__builtin_bit_cast(unsigned int, p[4 * g + 2]) >> 16) |
                        (__builtin_bit_cast(unsigned int, p[4 * g + 3]) & 0xFFFF0000u);
            }

            // Build PV B-frag for each K=16 slice s2 (m = m0 + s2*16 + hi*8 + j):
            //   dword0/1 (j0-3): owner hi=0's group 2s2+hi  (c0/c1)
            //   dword2/3 (j4-7): owner hi=1's group 2s2+hi  (c0/c1)
            // Partner exchange: each lane needs partner's c[2s2 + hi]; sending
            // c[2s2 + (hi^1)] through shfl_xor(,32) delivers exactly that.
            #pragma unroll
            for (int s2 = 0; s2 < 2; ++s2) {
                unsigned o00 = c0[2 * s2], o01 = c0[2 * s2 + 1];
                unsigned o10 = c1[2 * s2], o11 = c1[2 * s2 + 1];
                unsigned pr0 = (unsigned)__shfl_xor((int)(hi ? o00 : o01), 32);
                unsigned pr1 = (unsigned)__shfl_xor((int)(hi ? o10 : o11), 32);
                unsigned d0 = hi ? pr0 : o00;   // j0,1
                unsigned d1 = hi ? pr1 : o10;   // j2,3
                unsigned d2 = hi ? o01 : pr0;   // j4,5
                unsigned d3 = hi ? o11 : pr1;   // j6,7
                uint4 u = {d0, d1, d2, d3};
                bf16x8 pf = __builtin_bit_cast(bf16x8, u);
                #pragma unroll
                for (int ot2 = 0; ot2 < 2; ++ot2)
                    O[qt][ot2] = __builtin_amdgcn_mfma_f32_32x32x16_bf16(
                        va[ot2][s2], pf, O[qt][ot2], 0, 0, 0);
            }
        }
    }

    // ---- pair-combine over the M split (exp2-no-max: pure addition) ----
    if (mhalf) {
        float* ex = &comb[qpair][lane][0];
        *(f32x16*)&ex[0]  = O[0][0];
        *(f32x16*)&ex[16] = O[0][1];
        *(f32x16*)&ex[32] = O[1][0];
        *(f32x16*)&ex[48] = O[1][1];
        ex[64] = rs[0];
        ex[65] = rs[1];
    }
    __syncthreads();
    if (mhalf) return;

    {
        const float* ex = &comb[qpair][lane][0];
        f32x16 u00 = *(const f32x16*)&ex[0];
        f32x16 u01 = *(const f32x16*)&ex[16];
        f32x16 u10 = *(const f32x16*)&ex[32];
        f32x16 u11 = *(const f32x16*)&ex[48];
        O[0][0] += u00; O[0][1] += u01; O[1][0] += u10; O[1][1] += u11;
        rs[0] += ex[64];
        rs[1] += ex[65];
    }

    // softmax denominator: own 16 m-slots + partner half (lane^32)
    float inv[2];
    #pragma unroll
    for (int qt = 0; qt < 2; ++qt) {
        float x = rs[qt] + __shfl_xor(rs[qt], 32);
        inv[qt] = 1.0f / x;
    }

    const int b = bh >> 3, h = bh & 7;
    #pragma unroll
    for (int qt = 0; qt < 2; ++qt) {
        size_t grow = (size_t)b * N_ + n0w + qt * 32 + l31;
        unsigned short* orow = of + grow * C_ + h * HD_;
        #pragma unroll
        for (int ot2 = 0; ot2 < 2; ++ot2) {
            const int rgmax = (ot2 == 0) ? 4 : 2;    // d < 48
            #pragma unroll
            for (int rg = 0; rg < 4; ++rg) {
                if (rg >= rgmax) continue;
                int d0 = ot2 * 32 + rg * 8 + hi * 4;
                *(uint2*)(orow + d0) = pack4_rne(
                    O[qt][ot2][rg * 4 + 0] * inv[qt], O[qt][ot2][rg * 4 + 1] * inv[qt],
                    O[qt][ot2][rg * 4 + 2] * inv[qt], O[qt][ot2][rg * 4 + 3] * inv[qt]);
            }
        }
    }
}

extern "C" void kernel_launch(void* const* d_in, const int* in_sizes, int n_in,
                              void* d_out, int out_size, void* d_ws, size_t ws_size,
                              hipStream_t stream) {
    const float* q_x   = (const float*)d_in[0];
    const float* kv_x  = (const float*)d_in[1];
    const float* Wq    = (const float*)d_in[2];
    const float* Wkv   = (const float*)d_in[3];
    const float* Wproj = (const float*)d_in[4];
    const float* bproj = (const float*)d_in[5];
    float* out = (float*)d_out;

    unsigned short* qbf     = (unsigned short*)d_ws;  // [B,H,N,48] scaled
    unsigned short* kbf     = qbf     + 6291456;      // [B,H,M,48]
    unsigned short* vbf     = kbf     + 1572864;      // [B,H,48,M]
    unsigned short* of      = vbf     + 1572864;      // [B,N,384] bf16 attn out
    unsigned short* qx_bf   = of      + 6291456;      // [B,N,384] bf16
    unsigned short* kvx_bf  = qx_bf   + 6291456;      // [B,M,384] bf16
    unsigned short* Wq_t    = kvx_bf  + 1572864;      // [384][384]
    unsigned short* Wkv_t   = Wq_t    + 147456;       // [768][384]
    unsigned short* Wproj_t = Wkv_t   + 294912;       // [384][384]

    dim3 blk(256);

    // fused activation convert + weight transpose
    prep<<<dim3(7824), blk, 0, stream>>>(q_x, qx_bf, kv_x, kvx_bf,
                                         Wq, Wkv, Wproj, Wq_t, Wkv_t, Wproj_t);

    // fused q-proj + kv-proj (m97-style, global_load_lds staging)
    gemm_qkv<<<dim3(576), blk, 0, stream>>>(
        qx_bf, kvx_bf, Wq_t, Wkv_t, qbf, kbf, vbf);

    // attention: M-split pairs, 4 blocks/CU; two half-grid launches so the
    // other kernels surface in the rocprof top-5 (diagnostic)
    attn_mfma<<<dim3(32, 16), blk, 0, stream>>>(qbf, kbf, vbf, of, 0);
    attn_mfma<<<dim3(32, 16), blk, 0, stream>>>(qbf, kbf, vbf, of, 16);

    // out = q_res + of @ Wproj + bproj  (residual from qbf * 1/QSCALE)
    gemm_out<<<dim3(384), blk, 0, stream>>>(of, Wproj_t, out, qbf, bproj);
}

// Round 11
// 176.524 us; speedup vs baseline: 2.0003x; 2.0003x over previous
//
#include <hip/hip_runtime.h>
#include <hip/hip_bf16.h>
#include <math.h>

#define B_ 4
#define N_ 4096
#define M_ 1024
#define C_ 384
#define NH_ 8
#define HD_ 48

typedef float f32x4 __attribute__((ext_vector_type(4)));
typedef float f32x16 __attribute__((ext_vector_type(16)));
typedef short bf16x8 __attribute__((ext_vector_type(8)));

typedef __attribute__((address_space(3))) unsigned int lds_uint;
typedef const __attribute__((address_space(1))) unsigned int glob_uint;

__device__ __forceinline__ void gld_lds16(const void* g, void* l) {
    // async global->LDS, 16 B/lane; LDS dest = wave-uniform base + lane*16
    __builtin_amdgcn_global_load_lds((glob_uint*)g, (lds_uint*)l, 16, 0, 0);
}

__device__ __forceinline__ unsigned short f2bf(float x) {  // RNE
    unsigned int u = __builtin_bit_cast(unsigned int, x);
    return (unsigned short)((u + 0x7FFFu + ((u >> 16) & 1u)) >> 16);
}
__device__ __forceinline__ float bf2f(unsigned short x) {
    return __builtin_bit_cast(float, (unsigned int)x << 16);
}
__device__ __forceinline__ float fast_exp2(float x) {
#if __has_builtin(__builtin_amdgcn_exp2f)
    return __builtin_amdgcn_exp2f(x);
#else
    return exp2f(x);
#endif
}
__device__ __forceinline__ uint2 pack4_rne(float a, float b, float c, float d) {
    uint2 r;
    r.x = (unsigned int)f2bf(a) | ((unsigned int)f2bf(b) << 16);
    r.y = (unsigned int)f2bf(c) | ((unsigned int)f2bf(d) << 16);
    return r;
}

// 48^-0.5 * log2(e): softmax via 2^x
#define QSCALE 0.20823490983597203f
#define INV_QSCALE (1.0f / 0.20823490983597203f)

// ---------------------------------------------------------------------------
// Fused prep: blocks [0,7680) convert activations fp32->bf16 (flat float4
// grid; q_x then kv_x); blocks [7680,7824) transpose+convert weights.
// ---------------------------------------------------------------------------
__global__ __launch_bounds__(256)
void prep(const float* __restrict__ qx_f, unsigned short* __restrict__ qx_bf,
          const float* __restrict__ kvx_f, unsigned short* __restrict__ kvx_bf,
          const float* __restrict__ Wq, const float* __restrict__ Wkv,
          const float* __restrict__ Wproj,
          unsigned short* __restrict__ Wq_t, unsigned short* __restrict__ Wkv_t,
          unsigned short* __restrict__ Wproj_t)
{
    __shared__ unsigned short T[64 * 72];
    const int tid = threadIdx.x;
    int bid = blockIdx.x;

    if (bid < 7680) {
        size_t i4 = (size_t)bid * 256 + tid;
        const float* src; unsigned short* dst;
        if (i4 < 1572864u) { src = qx_f; dst = qx_bf; }
        else { src = kvx_f; dst = kvx_bf; i4 -= 1572864u; }
        float4 v = *(const float4*)&src[i4 * 4];
        *(uint2*)&dst[i4 * 4] = pack4_rne(v.x, v.y, v.z, v.w);
        return;
    }

    bid -= 7680;
    const float* W; unsigned short* Wt; int N, kt, nt;
    if (bid < 36)       { W = Wq;    Wt = Wq_t;    N = 384; kt = bid / 6;  nt = bid - kt * 6; }
    else if (bid < 108) { bid -= 36;  W = Wkv;   Wt = Wkv_t;   N = 768; kt = bid / 12; nt = bid - kt * 12; }
    else                { bid -= 108; W = Wproj; Wt = Wproj_t; N = 384; kt = bid / 6;  nt = bid - kt * 6; }
    const int k0 = kt * 64, n0 = nt * 64;

    #pragma unroll
    for (int it = 0; it < 4; ++it) {
        int k = it * 16 + (tid >> 4);
        int n4 = (tid & 15) * 4;
        float4 v = *(const float4*)&W[(size_t)(k0 + k) * N + n0 + n4];
        T[(n4 + 0) * 72 + k] = f2bf(v.x);
        T[(n4 + 1) * 72 + k] = f2bf(v.y);
        T[(n4 + 2) * 72 + k] = f2bf(v.z);
        T[(n4 + 3) * 72 + k] = f2bf(v.w);
    }
    __syncthreads();
    #pragma unroll
    for (int i = 0; i < 2; ++i) {
        int s = tid + 256 * i;
        int n = s >> 3, part = s & 7;
        *(uint4*)&Wt[(size_t)(n0 + n) * C_ + k0 + part * 8] = *(const uint4*)&T[n * 72 + part * 8];
    }
}

// ---------------------------------------------------------------------------
// m97-style GEMM core: 128x128 tile, BK=64, global_load_lds staging with
// XOR-8 chunk swizzle (conflict-free ds_read_b128, no padding needed).
// Single-buffered (R6 version; R8's double-buffer measured neutral).
// ---------------------------------------------------------------------------
__device__ __forceinline__ void stage128(const unsigned short* src, unsigned short* lds,
                                         int kk, int tid) {
    #pragma unroll
    for (int r = 0; r < 4; ++r) {
        int off = r * 256 + tid;          // 16B-slot index 0..1023
        int row = off >> 3;
        int c = off & 7;
        int gc = c ^ (row & 7);
        gld_lds16(src + (size_t)row * C_ + kk + gc * 8, lds + (size_t)off * 8);
    }
}
__device__ __forceinline__ bf16x8 frag_ld(const unsigned short* lds, int row, int chunk) {
    return *(const bf16x8*)&lds[row * 64 + ((chunk ^ (row & 7)) << 3)];
}

#define GEMM_CORE(Aptr, Wptr)                                                        \
    f32x4 acc[4][4];                                                                 \
    _Pragma("unroll")                                                                \
    for (int rt = 0; rt < 4; ++rt)                                                   \
        _Pragma("unroll")                                                            \
        for (int ct = 0; ct < 4; ++ct) acc[rt][ct] = (f32x4){0.f, 0.f, 0.f, 0.f};    \
    const int wrow0 = (wave & 1) * 64;                                               \
    const int wcol0 = (wave >> 1) * 64;                                              \
    for (int kk = 0; kk < C_; kk += 64) {                                            \
        __syncthreads();                                                             \
        stage128(Aptr, As, kk, tid);                                                 \
        stage128(Wptr, Ws, kk, tid);                                                 \
        __syncthreads();                                                             \
        _Pragma("unroll")                                                            \
        for (int ks = 0; ks < 2; ++ks) {                                             \
            bf16x8 af[4], wf[4];                                                     \
            _Pragma("unroll")                                                        \
            for (int rt = 0; rt < 4; ++rt)                                           \
                af[rt] = frag_ld(As, wrow0 + rt * 16 + ln, ks * 4 + quad);           \
            _Pragma("unroll")                                                        \
            for (int ct = 0; ct < 4; ++ct)                                           \
                wf[ct] = frag_ld(Ws, wcol0 + ct * 16 + ln, ks * 4 + quad);           \
            _Pragma("unroll")                                                        \
            for (int rt = 0; rt < 4; ++rt)                                           \
                _Pragma("unroll")                                                    \
                for (int ct = 0; ct < 4; ++ct)                                       \
                    acc[rt][ct] = __builtin_amdgcn_mfma_f32_16x16x32_bf16(           \
                        wf[ct], af[rt], acc[rt][ct], 0, 0, 0);                       \
        }                                                                            \
    }

// ---------------------------------------------------------------------------
// Fused q-proj (blocks [0,384)) + kv-proj (blocks [384,576)).
// ---------------------------------------------------------------------------
__global__ __launch_bounds__(256)
void gemm_qkv(const unsigned short* __restrict__ qx, const unsigned short* __restrict__ kvx,
              const unsigned short* __restrict__ Wqt, const unsigned short* __restrict__ Wkvt,
              unsigned short* __restrict__ qbf,
              unsigned short* __restrict__ kbf, unsigned short* __restrict__ vbf)
{
    __shared__ unsigned short As[128 * 64];
    __shared__ unsigned short Ws[128 * 64];
    const int tid = threadIdx.x;
    const int wave = tid >> 6;
    const int lane = tid & 63;
    const int ln = lane & 15;
    const int quad = lane >> 4;

    int bid = blockIdx.x;
    int mode, row0, col0;
    const unsigned short *A, *Wt;
    if (bid < 384) { mode = 0; A = qx;  Wt = Wqt;  row0 = (bid / 3) * 128; col0 = (bid % 3) * 128; }
    else { bid -= 384; mode = 1; A = kvx; Wt = Wkvt; row0 = (bid / 6) * 128; col0 = (bid % 6) * 128; }

    GEMM_CORE(A + (size_t)row0 * C_, Wt + (size_t)col0 * C_)

    #pragma unroll
    for (int rt = 0; rt < 4; ++rt) {
        int grow = row0 + wrow0 + rt * 16 + ln;
        #pragma unroll
        for (int ct = 0; ct < 4; ++ct) {
            int col = col0 + wcol0 + ct * 16 + quad * 4;
            f32x4 v = acc[rt][ct];
            if (mode == 0) {
                int b = grow >> 12, n = grow & (N_ - 1);
                int h = col / HD_, d = col - h * HD_;
                *(uint2*)&qbf[(((size_t)(b * NH_ + h) * N_) + n) * HD_ + d] =
                    pack4_rne(v[0] * QSCALE, v[1] * QSCALE, v[2] * QSCALE, v[3] * QSCALE);
            } else {
                int b = grow >> 10, m = grow & (M_ - 1);
                if (col < C_) {
                    int h = col / HD_, d = col - h * HD_;
                    *(uint2*)&kbf[(((size_t)(b * NH_ + h) * M_) + m) * HD_ + d] =
                        pack4_rne(v[0], v[1], v[2], v[3]);
                } else {
                    int c2 = col - C_;
                    int h = c2 / HD_, d = c2 - h * HD_;
                    size_t base = ((size_t)(b * NH_ + h) * HD_ + d) * M_ + m;
                    #pragma unroll
                    for (int r = 0; r < 4; ++r) vbf[base + (size_t)r * M_] = f2bf(v[r]);
                }
            }
        }
    }
}

// ---------------------------------------------------------------------------
// Out-proj: out = q_residual + of @ Wproj + bias. 384 blocks.
// Residual is reconstructed from qbf (scaled q) via 1/QSCALE — no qres buffer.
// ---------------------------------------------------------------------------
__global__ __launch_bounds__(256)
void gemm_out(const unsigned short* __restrict__ A, const unsigned short* __restrict__ Wt,
              float* __restrict__ out0,
              const unsigned short* __restrict__ qbf, const float* __restrict__ bias)
{
    __shared__ unsigned short As[128 * 64];
    __shared__ unsigned short Ws[128 * 64];
    const int tid = threadIdx.x;
    const int wave = tid >> 6;
    const int lane = tid & 63;
    const int ln = lane & 15;
    const int quad = lane >> 4;
    const int row0 = (blockIdx.x / 3) * 128;
    const int col0 = (blockIdx.x % 3) * 128;

    GEMM_CORE(A + (size_t)row0 * C_, Wt + (size_t)col0 * C_)

    #pragma unroll
    for (int rt = 0; rt < 4; ++rt) {
        int grow = row0 + wrow0 + rt * 16 + ln;
        #pragma unroll
        for (int ct = 0; ct < 4; ++ct) {
            int col = col0 + wcol0 + ct * 16 + quad * 4;
            f32x4 v = acc[rt][ct];
            size_t idx = (size_t)grow * C_ + col;
            int b = grow >> 12, n = grow & (N_ - 1);
            int h = col / HD_, d = col - h * HD_;
            uint2 ad = *(const uint2*)&qbf[(((size_t)(b * NH_ + h) * N_) + n) * HD_ + d];
            float4 bi = *(const float4*)&bias[col];
            float4 o;
            o.x = v[0] + bf2f((unsigned short)(ad.x & 0xFFFF)) * INV_QSCALE + bi.x;
            o.y = v[1] + bf2f((unsigned short)(ad.x >> 16))    * INV_QSCALE + bi.y;
            o.z = v[2] + bf2f((unsigned short)(ad.y & 0xFFFF)) * INV_QSCALE + bi.z;
            o.w = v[3] + bf2f((unsigned short)(ad.y >> 16))    * INV_QSCALE + bi.w;
            *(float4*)&out0[idx] = o;
        }
    }
}

// ---------------------------------------------------------------------------
// MFMA attention R17 (resubmit; R10 was an infra failure, never measured):
// the R16 M-split body (verified correct in R9), launched right: ONE launch
// of grid (32,32) = 1024 blocks (R9's two half-launches serialized at
// 2 blocks/CU each), and __launch_bounds__(256,2) instead of (256,4) — the
// min-waves>=4 bound made the allocator squeeze to 64 VGPR and spill ~500 MB
// of scratch (R2/R4/R9, 3x confirmed). With natural ~100 VGPR and 36 KB LDS
// the HARDWARE limit is already 4 blocks/CU = 4 waves/SIMD; no hint needed.
// Wave w: qpair = w>>1 (64 q-rows), mhalf = w&1 (mtt in [mhalf*16, +16)).
// M-split halves loads and MFMA equally (amortization preserved) and keeps
// the qt=2 ILP chains. Combine: exp2-no-max softmax => partials add.
// ---------------------------------------------------------------------------
__global__ __launch_bounds__(256, 2)
void attn_mfma(const unsigned short* __restrict__ qbf,
               const unsigned short* __restrict__ kbf,
               const unsigned short* __restrict__ vbf,
               unsigned short* __restrict__ of)
{
    __shared__ float comb[2][64][72];   // [qpair][lane][72]

    const int tid = threadIdx.x;
    const int wave = tid >> 6;
    const int qpair = wave >> 1;
    const int mhalf = wave & 1;
    const int lane = tid & 63;
    const int l31 = lane & 31;
    const int hi  = lane >> 5;       // 0: k 0-7, 1: k 8-15 within a K=16 slice
    const int bh = blockIdx.x;
    const int n0w = blockIdx.y * 128 + qpair * 64;

    const unsigned short* kb = kbf + (size_t)bh * M_ * HD_;
    const unsigned short* vb = vbf + (size_t)bh * HD_ * M_;

    // Q B-fragments: qb[qt][s] = Q[q = n0w+qt*32+l31][k = s*16 + hi*8 + 0..7]
    bf16x8 qb[2][3];
    #pragma unroll
    for (int qt = 0; qt < 2; ++qt) {
        const unsigned short* qp = qbf + ((size_t)bh * N_ + n0w + qt * 32 + l31) * HD_;
        #pragma unroll
        for (int s = 0; s < 3; ++s)
            qb[qt][s] = *(const bf16x8*)(qp + s * 16 + hi * 8);
    }

    f32x16 O[2][2];   // [qt][ot2]; rows d = ot2*32 + (reg&3)+8*(reg>>2)+4*hi
    #pragma unroll
    for (int qt = 0; qt < 2; ++qt)
        #pragma unroll
        for (int ot2 = 0; ot2 < 2; ++ot2)
            #pragma unroll
            for (int r = 0; r < 16; ++r) O[qt][ot2][r] = 0.f;
    float rs[2] = {0.f, 0.f};

    const int mtt0 = mhalf * 16;
    for (int mtt = mtt0; mtt < mtt0 + 16; ++mtt) {     // 32 m-rows per iter
        const int m0 = mtt * 32;

        // K A-fragments: ka[s] = K[m = m0+l31][k = s*16 + hi*8 + 0..7]
        bf16x8 ka[3];
        #pragma unroll
        for (int s = 0; s < 3; ++s)
            ka[s] = *(const bf16x8*)&kb[(size_t)(m0 + l31) * HD_ + s * 16 + hi * 8];

        // V A-fragments: va[ot2][s2] = V[d = ot2*32+l31][m = m0 + s2*16 + hi*8 + 0..7]
        // ot2=1 rows 48..63 overread next bh's V / of-region: any bf16 bits ok,
        // they only feed dead acc rows.
        bf16x8 va[2][2];
        #pragma unroll
        for (int ot2 = 0; ot2 < 2; ++ot2)
            #pragma unroll
            for (int s2 = 0; s2 < 2; ++s2)
                va[ot2][s2] = *(const bf16x8*)&vb[(size_t)(ot2 * 32 + l31) * M_ + m0 + s2 * 16 + hi * 8];

        #pragma unroll
        for (int qt = 0; qt < 2; ++qt) {
            f32x16 S;
            #pragma unroll
            for (int r = 0; r < 16; ++r) S[r] = 0.f;
            #pragma unroll
            for (int s = 0; s < 3; ++s)
                S = __builtin_amdgcn_mfma_f32_32x32x16_bf16(ka[s], qb[qt][s], S, 0, 0, 0);

            // lane holds S[m_local = (r&3) + 8*(r>>2) + 4*hi][q = l31]
            float p[16];
            #pragma unroll
            for (int r = 0; r < 16; ++r) p[r] = fast_exp2(S[r]);
            // pairwise sum (short dep chain)
            {
                float s0 = (p[0] + p[1]) + (p[2] + p[3]);
                float s1 = (p[4] + p[5]) + (p[6] + p[7]);
                float s2 = (p[8] + p[9]) + (p[10] + p[11]);
                float s3 = (p[12] + p[13]) + (p[14] + p[15]);
                rs[qt] += (s0 + s1) + (s2 + s3);
            }

            // pack groups g (own m-range 8g+4*hi .. +3):
            // c0[g] = {p[4g], p[4g+1]}, c1[g] = {p[4g+2], p[4g+3]}  (trunc-to-bf16)
            unsigned c0[4], c1[4];
            #pragma unroll
            for (int g = 0; g < 4; ++g) {
                c0[g] = (__builtin_bit_cast(unsigned int, p[4 * g + 0]) >> 16) |
                        (__builtin_bit_cast(unsigned int, p[4 * g + 1]) & 0xFFFF0000u);
                c1[g] = (__builtin_bit_cast(unsigned int, p[4 * g + 2]) >> 16) |
                        (__builtin_bit_cast(unsigned int, p[4 * g + 3]) & 0xFFFF0000u);
            }

            // Build PV B-frag for each K=16 slice s2 (m = m0 + s2*16 + hi*8 + j):
            //   dword0/1 (j0-3): owner hi=0's group 2s2+hi  (c0/c1)
            //   dword2/3 (j4-7): owner hi=1's group 2s2+hi  (c0/c1)
            // Partner exchange: each lane needs partner's c[2s2 + hi]; sending
            // c[2s2 + (hi^1)] through shfl_xor(,32) delivers exactly that.
            #pragma unroll
            for (int s2 = 0; s2 < 2; ++s2) {
                unsigned o00 = c0[2 * s2], o01 = c0[2 * s2 + 1];
                unsigned o10 = c1[2 * s2], o11 = c1[2 * s2 + 1];
                unsigned pr0 = (unsigned)__shfl_xor((int)(hi ? o00 : o01), 32);
                unsigned pr1 = (unsigned)__shfl_xor((int)(hi ? o10 : o11), 32);
                unsigned d0 = hi ? pr0 : o00;   // j0,1
                unsigned d1 = hi ? pr1 : o10;   // j2,3
                unsigned d2 = hi ? o01 : pr0;   // j4,5
                unsigned d3 = hi ? o11 : pr1;   // j6,7
                uint4 u = {d0, d1, d2, d3};
                bf16x8 pf = __builtin_bit_cast(bf16x8, u);
                #pragma unroll
                for (int ot2 = 0; ot2 < 2; ++ot2)
                    O[qt][ot2] = __builtin_amdgcn_mfma_f32_32x32x16_bf16(
                        va[ot2][s2], pf, O[qt][ot2], 0, 0, 0);
            }
        }
    }

    // ---- pair-combine over the M split (exp2-no-max: pure addition) ----
    if (mhalf) {
        float* ex = &comb[qpair][lane][0];
        *(f32x16*)&ex[0]  = O[0][0];
        *(f32x16*)&ex[16] = O[0][1];
        *(f32x16*)&ex[32] = O[1][0];
        *(f32x16*)&ex[48] = O[1][1];
        ex[64] = rs[0];
        ex[65] = rs[1];
    }
    __syncthreads();
    if (mhalf) return;

    {
        const float* ex = &comb[qpair][lane][0];
        f32x16 u00 = *(const f32x16*)&ex[0];
        f32x16 u01 = *(const f32x16*)&ex[16];
        f32x16 u10 = *(const f32x16*)&ex[32];
        f32x16 u11 = *(const f32x16*)&ex[48];
        O[0][0] += u00; O[0][1] += u01; O[1][0] += u10; O[1][1] += u11;
        rs[0] += ex[64];
        rs[1] += ex[65];
    }

    // softmax denominator: own 16 m-slots + partner half (lane^32)
    float inv[2];
    #pragma unroll
    for (int qt = 0; qt < 2; ++qt) {
        float x = rs[qt] + __shfl_xor(rs[qt], 32);
        inv[qt] = 1.0f / x;
    }

    const int b = bh >> 3, h = bh & 7;
    #pragma unroll
    for (int qt = 0; qt < 2; ++qt) {
        size_t grow = (size_t)b * N_ + n0w + qt * 32 + l31;
        unsigned short* orow = of + grow * C_ + h * HD_;
        #pragma unroll
        for (int ot2 = 0; ot2 < 2; ++ot2) {
            const int rgmax = (ot2 == 0) ? 4 : 2;    // d < 48
            #pragma unroll
            for (int rg = 0; rg < 4; ++rg) {
                if (rg >= rgmax) continue;
                int d0 = ot2 * 32 + rg * 8 + hi * 4;
                *(uint2*)(orow + d0) = pack4_rne(
                    O[qt][ot2][rg * 4 + 0] * inv[qt], O[qt][ot2][rg * 4 + 1] * inv[qt],
                    O[qt][ot2][rg * 4 + 2] * inv[qt], O[qt][ot2][rg * 4 + 3] * inv[qt]);
            }
        }
    }
}

extern "C" void kernel_launch(void* const* d_in, const int* in_sizes, int n_in,
                              void* d_out, int out_size, void* d_ws, size_t ws_size,
                              hipStream_t stream) {
    const float* q_x   = (const float*)d_in[0];
    const float* kv_x  = (const float*)d_in[1];
    const float* Wq    = (const float*)d_in[2];
    const float* Wkv   = (const float*)d_in[3];
    const float* Wproj = (const float*)d_in[4];
    const float* bproj = (const float*)d_in[5];
    float* out = (float*)d_out;

    unsigned short* qbf     = (unsigned short*)d_ws;  // [B,H,N,48] scaled
    unsigned short* kbf     = qbf     + 6291456;      // [B,H,M,48]
    unsigned short* vbf     = kbf     + 1572864;      // [B,H,48,M]
    unsigned short* of      = vbf     + 1572864;      // [B,N,384] bf16 attn out
    unsigned short* qx_bf   = of      + 6291456;      // [B,N,384] bf16
    unsigned short* kvx_bf  = qx_bf   + 6291456;      // [B,M,384] bf16
    unsigned short* Wq_t    = kvx_bf  + 1572864;      // [384][384]
    unsigned short* Wkv_t   = Wq_t    + 147456;       // [768][384]
    unsigned short* Wproj_t = Wkv_t   + 294912;       // [384][384]

    dim3 blk(256);

    // fused activation convert + weight transpose
    prep<<<dim3(7824), blk, 0, stream>>>(q_x, qx_bf, kv_x, kvx_bf,
                                         Wq, Wkv, Wproj, Wq_t, Wkv_t, Wproj_t);

    // fused q-proj + kv-proj (m97-style, global_load_lds staging)
    gemm_qkv<<<dim3(576), blk, 0, stream>>>(
        qx_bf, kvx_bf, Wq_t, Wkv_t, qbf, kbf, vbf);

    // attention: M-split wave pairs, ONE launch of 1024 blocks (4 blocks/CU)
    attn_mfma<<<dim3(32, 32), blk, 0, stream>>>(qbf, kbf, vbf, of);

    // out = q_res + of @ Wproj + bproj  (residual from qbf * 1/QSCALE)
    gemm_out<<<dim3(384), blk, 0, stream>>>(of, Wproj_t, out, qbf, bproj);
}

// Round 12
// 168.612 us; speedup vs baseline: 2.0941x; 1.0469x over previous
//
#include <hip/hip_runtime.h>
#include <hip/hip_bf16.h>
#include <math.h>

#define B_ 4
#define N_ 4096
#define M_ 1024
#define C_ 384
#define NH_ 8
#define HD_ 48

typedef float f32x4 __attribute__((ext_vector_type(4)));
typedef float f32x16 __attribute__((ext_vector_type(16)));
typedef short bf16x8 __attribute__((ext_vector_type(8)));

typedef __attribute__((address_space(3))) unsigned int lds_uint;
typedef const __attribute__((address_space(1))) unsigned int glob_uint;

__device__ __forceinline__ void gld_lds16(const void* g, void* l) {
    // async global->LDS, 16 B/lane; LDS dest = wave-uniform base + lane*16
    __builtin_amdgcn_global_load_lds((glob_uint*)g, (lds_uint*)l, 16, 0, 0);
}

__device__ __forceinline__ unsigned short f2bf(float x) {  // RNE
    unsigned int u = __builtin_bit_cast(unsigned int, x);
    return (unsigned short)((u + 0x7FFFu + ((u >> 16) & 1u)) >> 16);
}
__device__ __forceinline__ float bf2f(unsigned short x) {
    return __builtin_bit_cast(float, (unsigned int)x << 16);
}
__device__ __forceinline__ float fast_exp2(float x) {
#if __has_builtin(__builtin_amdgcn_exp2f)
    return __builtin_amdgcn_exp2f(x);
#else
    return exp2f(x);
#endif
}
__device__ __forceinline__ uint2 pack4_rne(float a, float b, float c, float d) {
    uint2 r;
    r.x = (unsigned int)f2bf(a) | ((unsigned int)f2bf(b) << 16);
    r.y = (unsigned int)f2bf(c) | ((unsigned int)f2bf(d) << 16);
    return r;
}

// 48^-0.5 * log2(e): softmax via 2^x
#define QSCALE 0.20823490983597203f
#define INV_QSCALE (1.0f / 0.20823490983597203f)

// ---------------------------------------------------------------------------
// Fused prep: blocks [0,7680) convert activations fp32->bf16 (flat float4
// grid; q_x then kv_x); blocks [7680,7824) transpose+convert weights.
// ---------------------------------------------------------------------------
__global__ __launch_bounds__(256)
void prep(const float* __restrict__ qx_f, unsigned short* __restrict__ qx_bf,
          const float* __restrict__ kvx_f, unsigned short* __restrict__ kvx_bf,
          const float* __restrict__ Wq, const float* __restrict__ Wkv,
          const float* __restrict__ Wproj,
          unsigned short* __restrict__ Wq_t, unsigned short* __restrict__ Wkv_t,
          unsigned short* __restrict__ Wproj_t)
{
    __shared__ unsigned short T[64 * 72];
    const int tid = threadIdx.x;
    int bid = blockIdx.x;

    if (bid < 7680) {
        size_t i4 = (size_t)bid * 256 + tid;
        const float* src; unsigned short* dst;
        if (i4 < 1572864u) { src = qx_f; dst = qx_bf; }
        else { src = kvx_f; dst = kvx_bf; i4 -= 1572864u; }
        float4 v = *(const float4*)&src[i4 * 4];
        *(uint2*)&dst[i4 * 4] = pack4_rne(v.x, v.y, v.z, v.w);
        return;
    }

    bid -= 7680;
    const float* W; unsigned short* Wt; int N, kt, nt;
    if (bid < 36)       { W = Wq;    Wt = Wq_t;    N = 384; kt = bid / 6;  nt = bid - kt * 6; }
    else if (bid < 108) { bid -= 36;  W = Wkv;   Wt = Wkv_t;   N = 768; kt = bid / 12; nt = bid - kt * 12; }
    else                { bid -= 108; W = Wproj; Wt = Wproj_t; N = 384; kt = bid / 6;  nt = bid - kt * 6; }
    const int k0 = kt * 64, n0 = nt * 64;

    #pragma unroll
    for (int it = 0; it < 4; ++it) {
        int k = it * 16 + (tid >> 4);
        int n4 = (tid & 15) * 4;
        float4 v = *(const float4*)&W[(size_t)(k0 + k) * N + n0 + n4];
        T[(n4 + 0) * 72 + k] = f2bf(v.x);
        T[(n4 + 1) * 72 + k] = f2bf(v.y);
        T[(n4 + 2) * 72 + k] = f2bf(v.z);
        T[(n4 + 3) * 72 + k] = f2bf(v.w);
    }
    __syncthreads();
    #pragma unroll
    for (int i = 0; i < 2; ++i) {
        int s = tid + 256 * i;
        int n = s >> 3, part = s & 7;
        *(uint4*)&Wt[(size_t)(n0 + n) * C_ + k0 + part * 8] = *(const uint4*)&T[n * 72 + part * 8];
    }
}

// ---------------------------------------------------------------------------
// m97-style GEMM staging helpers: XOR-8 chunk swizzle, conflict-free
// ds_read_b128. stage128 = 128 rows x 64 cols; stage64 = 64 rows x 64 cols.
// ---------------------------------------------------------------------------
__device__ __forceinline__ void stage128(const unsigned short* src, unsigned short* lds,
                                         int kk, int tid) {
    #pragma unroll
    for (int r = 0; r < 4; ++r) {
        int off = r * 256 + tid;          // 16B-slot index 0..1023
        int row = off >> 3;
        int c = off & 7;
        int gc = c ^ (row & 7);
        gld_lds16(src + (size_t)row * C_ + kk + gc * 8, lds + (size_t)off * 8);
    }
}
__device__ __forceinline__ void stage64(const unsigned short* src, unsigned short* lds,
                                        int kk, int tid) {
    #pragma unroll
    for (int r = 0; r < 2; ++r) {
        int off = r * 256 + tid;          // 16B-slot index 0..511
        int row = off >> 3;
        int c = off & 7;
        int gc = c ^ (row & 7);
        gld_lds16(src + (size_t)row * C_ + kk + gc * 8, lds + (size_t)off * 8);
    }
}
__device__ __forceinline__ bf16x8 frag_ld(const unsigned short* lds, int row, int chunk) {
    return *(const bf16x8*)&lds[row * 64 + ((chunk ^ (row & 7)) << 3)];
}

#define GEMM_CORE(Aptr, Wptr)                                                        \
    f32x4 acc[4][4];                                                                 \
    _Pragma("unroll")                                                                \
    for (int rt = 0; rt < 4; ++rt)                                                   \
        _Pragma("unroll")                                                            \
        for (int ct = 0; ct < 4; ++ct) acc[rt][ct] = (f32x4){0.f, 0.f, 0.f, 0.f};    \
    const int wrow0 = (wave & 1) * 64;                                               \
    const int wcol0 = (wave >> 1) * 64;                                              \
    for (int kk = 0; kk < C_; kk += 64) {                                            \
        __syncthreads();                                                             \
        stage128(Aptr, As, kk, tid);                                                 \
        stage128(Wptr, Ws, kk, tid);                                                 \
        __syncthreads();                                                             \
        _Pragma("unroll")                                                            \
        for (int ks = 0; ks < 2; ++ks) {                                             \
            bf16x8 af[4], wf[4];                                                     \
            _Pragma("unroll")                                                        \
            for (int rt = 0; rt < 4; ++rt)                                           \
                af[rt] = frag_ld(As, wrow0 + rt * 16 + ln, ks * 4 + quad);           \
            _Pragma("unroll")                                                        \
            for (int ct = 0; ct < 4; ++ct)                                           \
                wf[ct] = frag_ld(Ws, wcol0 + ct * 16 + ln, ks * 4 + quad);           \
            _Pragma("unroll")                                                        \
            for (int rt = 0; rt < 4; ++rt)                                           \
                _Pragma("unroll")                                                    \
                for (int ct = 0; ct < 4; ++ct)                                       \
                    acc[rt][ct] = __builtin_amdgcn_mfma_f32_16x16x32_bf16(           \
                        wf[ct], af[rt], acc[rt][ct], 0, 0, 0);                       \
        }                                                                            \
    }

// ---------------------------------------------------------------------------
// Fused q-proj (blocks [0,384)) + kv-proj (blocks [384,576)).
// ---------------------------------------------------------------------------
__global__ __launch_bounds__(256)
void gemm_qkv(const unsigned short* __restrict__ qx, const unsigned short* __restrict__ kvx,
              const unsigned short* __restrict__ Wqt, const unsigned short* __restrict__ Wkvt,
              unsigned short* __restrict__ qbf,
              unsigned short* __restrict__ kbf, unsigned short* __restrict__ vbf)
{
    __shared__ unsigned short As[128 * 64];
    __shared__ unsigned short Ws[128 * 64];
    const int tid = threadIdx.x;
    const int wave = tid >> 6;
    const int lane = tid & 63;
    const int ln = lane & 15;
    const int quad = lane >> 4;

    int bid = blockIdx.x;
    int mode, row0, col0;
    const unsigned short *A, *Wt;
    if (bid < 384) { mode = 0; A = qx;  Wt = Wqt;  row0 = (bid / 3) * 128; col0 = (bid % 3) * 128; }
    else { bid -= 384; mode = 1; A = kvx; Wt = Wkvt; row0 = (bid / 6) * 128; col0 = (bid % 6) * 128; }

    GEMM_CORE(A + (size_t)row0 * C_, Wt + (size_t)col0 * C_)

    #pragma unroll
    for (int rt = 0; rt < 4; ++rt) {
        int grow = row0 + wrow0 + rt * 16 + ln;
        #pragma unroll
        for (int ct = 0; ct < 4; ++ct) {
            int col = col0 + wcol0 + ct * 16 + quad * 4;
            f32x4 v = acc[rt][ct];
            if (mode == 0) {
                int b = grow >> 12, n = grow & (N_ - 1);
                int h = col / HD_, d = col - h * HD_;
                *(uint2*)&qbf[(((size_t)(b * NH_ + h) * N_) + n) * HD_ + d] =
                    pack4_rne(v[0] * QSCALE, v[1] * QSCALE, v[2] * QSCALE, v[3] * QSCALE);
            } else {
                int b = grow >> 10, m = grow & (M_ - 1);
                if (col < C_) {
                    int h = col / HD_, d = col - h * HD_;
                    *(uint2*)&kbf[(((size_t)(b * NH_ + h) * M_) + m) * HD_ + d] =
                        pack4_rne(v[0], v[1], v[2], v[3]);
                } else {
                    int c2 = col - C_;
                    int h = c2 / HD_, d = c2 - h * HD_;
                    size_t base = ((size_t)(b * NH_ + h) * HD_ + d) * M_ + m;
                    #pragma unroll
                    for (int r = 0; r < 4; ++r) vbf[base + (size_t)r * M_] = f2bf(v[r]);
                }
            }
        }
    }
}

// ---------------------------------------------------------------------------
// Out-proj R18: 128x64 tiles -> 768 blocks = 3 blocks/CU (was 384 = 1.5,
// grid-capped occupancy, same disease attn had in R0). 24 KB LDS. Same
// total MFMA count; A re-staged 6x instead of 3x across col tiles (L2 hit).
// out = q_residual + of @ Wproj + bias; residual reconstructed from qbf.
// ---------------------------------------------------------------------------
__global__ __launch_bounds__(256)
void gemm_out(const unsigned short* __restrict__ A, const unsigned short* __restrict__ Wt,
              float* __restrict__ out0,
              const unsigned short* __restrict__ qbf, const float* __restrict__ bias)
{
    __shared__ unsigned short As[128 * 64];
    __shared__ unsigned short Ws[64 * 64];
    const int tid = threadIdx.x;
    const int wave = tid >> 6;
    const int lane = tid & 63;
    const int ln = lane & 15;
    const int quad = lane >> 4;
    const int row0 = (blockIdx.x / 6) * 128;
    const int col0 = (blockIdx.x % 6) * 64;
    const int wrow0 = (wave & 1) * 64;
    const int wcol0 = (wave >> 1) * 32;

    f32x4 acc[4][2];
    #pragma unroll
    for (int rt = 0; rt < 4; ++rt)
        #pragma unroll
        for (int ct = 0; ct < 2; ++ct) acc[rt][ct] = (f32x4){0.f, 0.f, 0.f, 0.f};

    const unsigned short* Ap = A + (size_t)row0 * C_;
    const unsigned short* Wp = Wt + (size_t)col0 * C_;
    for (int kk = 0; kk < C_; kk += 64) {
        __syncthreads();
        stage128(Ap, As, kk, tid);
        stage64(Wp, Ws, kk, tid);
        __syncthreads();
        #pragma unroll
        for (int ks = 0; ks < 2; ++ks) {
            bf16x8 af[4], wf[2];
            #pragma unroll
            for (int rt = 0; rt < 4; ++rt)
                af[rt] = frag_ld(As, wrow0 + rt * 16 + ln, ks * 4 + quad);
            #pragma unroll
            for (int ct = 0; ct < 2; ++ct)
                wf[ct] = frag_ld(Ws, wcol0 + ct * 16 + ln, ks * 4 + quad);
            #pragma unroll
            for (int rt = 0; rt < 4; ++rt)
                #pragma unroll
                for (int ct = 0; ct < 2; ++ct)
                    acc[rt][ct] = __builtin_amdgcn_mfma_f32_16x16x32_bf16(
                        wf[ct], af[rt], acc[rt][ct], 0, 0, 0);
        }
    }

    #pragma unroll
    for (int rt = 0; rt < 4; ++rt) {
        int grow = row0 + wrow0 + rt * 16 + ln;
        #pragma unroll
        for (int ct = 0; ct < 2; ++ct) {
            int col = col0 + wcol0 + ct * 16 + quad * 4;
            f32x4 v = acc[rt][ct];
            size_t idx = (size_t)grow * C_ + col;
            int b = grow >> 12, n = grow & (N_ - 1);
            int h = col / HD_, d = col - h * HD_;
            uint2 ad = *(const uint2*)&qbf[(((size_t)(b * NH_ + h) * N_) + n) * HD_ + d];
            float4 bi = *(const float4*)&bias[col];
            float4 o;
            o.x = v[0] + bf2f((unsigned short)(ad.x & 0xFFFF)) * INV_QSCALE + bi.x;
            o.y = v[1] + bf2f((unsigned short)(ad.x >> 16))    * INV_QSCALE + bi.y;
            o.z = v[2] + bf2f((unsigned short)(ad.y & 0xFFFF)) * INV_QSCALE + bi.z;
            o.w = v[3] + bf2f((unsigned short)(ad.y >> 16))    * INV_QSCALE + bi.w;
            *(float4*)&out0[idx] = o;
        }
    }
}

// ---------------------------------------------------------------------------
// MFMA attention R18: R12 body (best measured, 50 us) + T14 register
// double-buffer prefetch (issue iter N+1's 7 K/V loads BEFORE iter N's
// compute: removes the ~200-500 cyc L2 latency from each iteration head;
// +17% on m214's attn) + T5 s_setprio around MFMA clusters (+4-7% on
// barrier-free attn, m191). Same shape as R12: 4 waves x 64 q-rows,
// grid (32,16), 2 blocks/CU, launch_bounds (256,2) (never min-waves>=4:
// allocator squeezes to 64 VGPR and spills — 3x confirmed).
// ---------------------------------------------------------------------------
__device__ __forceinline__ void attn_load(bf16x8 (&ka)[3], bf16x8 (&va)[2][2],
                                          const unsigned short* kb,
                                          const unsigned short* vb,
                                          int m0, int l31, int hi)
{
    #pragma unroll
    for (int s = 0; s < 3; ++s)
        ka[s] = *(const bf16x8*)&kb[(size_t)(m0 + l31) * HD_ + s * 16 + hi * 8];
    // ot2=1 rows 48..63 overread next bh's V / of-region: bits only feed
    // dead acc rows (d >= 48, never written out).
    #pragma unroll
    for (int ot2 = 0; ot2 < 2; ++ot2)
        #pragma unroll
        for (int s2 = 0; s2 < 2; ++s2)
            va[ot2][s2] = *(const bf16x8*)&vb[(size_t)(ot2 * 32 + l31) * M_ + m0 + s2 * 16 + hi * 8];
}

__device__ __forceinline__ void attn_compute(const bf16x8 (&ka)[3], const bf16x8 (&va)[2][2],
                                             const bf16x8 (&qb)[2][3],
                                             f32x16 (&O)[2][2], float (&rs)[2], int hi)
{
    #pragma unroll
    for (int qt = 0; qt < 2; ++qt) {
        f32x16 S;
        #pragma unroll
        for (int r = 0; r < 16; ++r) S[r] = 0.f;
        __builtin_amdgcn_s_setprio(1);
        #pragma unroll
        for (int s = 0; s < 3; ++s)
            S = __builtin_amdgcn_mfma_f32_32x32x16_bf16(ka[s], qb[qt][s], S, 0, 0, 0);
        __builtin_amdgcn_s_setprio(0);

        // lane holds S[m_local = (r&3) + 8*(r>>2) + 4*hi][q = l31]
        float p[16];
        #pragma unroll
        for (int r = 0; r < 16; ++r) p[r] = fast_exp2(S[r]);
        {
            float s0 = (p[0] + p[1]) + (p[2] + p[3]);
            float s1 = (p[4] + p[5]) + (p[6] + p[7]);
            float s2 = (p[8] + p[9]) + (p[10] + p[11]);
            float s3 = (p[12] + p[13]) + (p[14] + p[15]);
            rs[qt] += (s0 + s1) + (s2 + s3);
        }

        // pack groups g: c0[g] = {p[4g], p[4g+1]}, c1[g] = {p[4g+2], p[4g+3]}
        unsigned c0[4], c1[4];
        #pragma unroll
        for (int g = 0; g < 4; ++g) {
            c0[g] = (__builtin_bit_cast(unsigned int, p[4 * g + 0]) >> 16) |
                    (__builtin_bit_cast(unsigned int, p[4 * g + 1]) & 0xFFFF0000u);
            c1[g] = (__builtin_bit_cast(unsigned int, p[4 * g + 2]) >> 16) |
                    (__builtin_bit_cast(unsigned int, p[4 * g + 3]) & 0xFFFF0000u);
        }

        // PV B-frag per K=16 slice s2: partner exchange via shfl_xor(,32) —
        // each lane needs partner's c[2s2 + hi]; send c[2s2 + (hi^1)].
        #pragma unroll
        for (int s2 = 0; s2 < 2; ++s2) {
            unsigned o00 = c0[2 * s2], o01 = c0[2 * s2 + 1];
            unsigned o10 = c1[2 * s2], o11 = c1[2 * s2 + 1];
            unsigned pr0 = (unsigned)__shfl_xor((int)(hi ? o00 : o01), 32);
            unsigned pr1 = (unsigned)__shfl_xor((int)(hi ? o10 : o11), 32);
            unsigned d0 = hi ? pr0 : o00;   // j0,1
            unsigned d1 = hi ? pr1 : o10;   // j2,3
            unsigned d2 = hi ? o01 : pr0;   // j4,5
            unsigned d3 = hi ? o11 : pr1;   // j6,7
            uint4 u = {d0, d1, d2, d3};
            bf16x8 pf = __builtin_bit_cast(bf16x8, u);
            __builtin_amdgcn_s_setprio(1);
            #pragma unroll
            for (int ot2 = 0; ot2 < 2; ++ot2)
                O[qt][ot2] = __builtin_amdgcn_mfma_f32_32x32x16_bf16(
                    va[ot2][s2], pf, O[qt][ot2], 0, 0, 0);
            __builtin_amdgcn_s_setprio(0);
        }
    }
}

__global__ __launch_bounds__(256, 2)
void attn_mfma(const unsigned short* __restrict__ qbf,
               const unsigned short* __restrict__ kbf,
               const unsigned short* __restrict__ vbf,
               unsigned short* __restrict__ of)
{
    const int tid = threadIdx.x;
    const int wave = tid >> 6;
    const int lane = tid & 63;
    const int l31 = lane & 31;
    const int hi  = lane >> 5;       // 0: k 0-7, 1: k 8-15 within a K=16 slice
    const int bh = blockIdx.x;
    const int n0w = blockIdx.y * 256 + wave * 64;

    const unsigned short* kb = kbf + (size_t)bh * M_ * HD_;
    const unsigned short* vb = vbf + (size_t)bh * HD_ * M_;

    // Q B-fragments: qb[qt][s] = Q[q = n0w+qt*32+l31][k = s*16 + hi*8 + 0..7]
    bf16x8 qb[2][3];
    #pragma unroll
    for (int qt = 0; qt < 2; ++qt) {
        const unsigned short* qp = qbf + ((size_t)bh * N_ + n0w + qt * 32 + l31) * HD_;
        #pragma unroll
        for (int s = 0; s < 3; ++s)
            qb[qt][s] = *(const bf16x8*)(qp + s * 16 + hi * 8);
    }

    f32x16 O[2][2];   // [qt][ot2]; rows d = ot2*32 + (reg&3)+8*(reg>>2)+4*hi
    #pragma unroll
    for (int qt = 0; qt < 2; ++qt)
        #pragma unroll
        for (int ot2 = 0; ot2 < 2; ++ot2)
            #pragma unroll
            for (int r = 0; r < 16; ++r) O[qt][ot2][r] = 0.f;
    float rs[2] = {0.f, 0.f};

    // register double-buffer: A holds current iter's fragments, B next's.
    bf16x8 kaA[3], vaA[2][2], kaB[3], vaB[2][2];
    attn_load(kaA, vaA, kb, vb, 0, l31, hi);

    for (int mtt = 0; mtt < 32; mtt += 2) {
        attn_load(kaB, vaB, kb, vb, (mtt + 1) * 32, l31, hi);   // prefetch
        attn_compute(kaA, vaA, qb, O, rs, hi);
        if (mtt + 2 < 32)
            attn_load(kaA, vaA, kb, vb, (mtt + 2) * 32, l31, hi);  // prefetch
        attn_compute(kaB, vaB, qb, O, rs, hi);
    }

    // softmax denominator: own 16 m-slots + partner half
    float inv[2];
    #pragma unroll
    for (int qt = 0; qt < 2; ++qt) {
        float x = rs[qt] + __shfl_xor(rs[qt], 32);
        inv[qt] = 1.0f / x;
    }

    const int b = bh >> 3, h = bh & 7;
    #pragma unroll
    for (int qt = 0; qt < 2; ++qt) {
        size_t grow = (size_t)b * N_ + n0w + qt * 32 + l31;
        unsigned short* orow = of + grow * C_ + h * HD_;
        #pragma unroll
        for (int ot2 = 0; ot2 < 2; ++ot2) {
            const int rgmax = (ot2 == 0) ? 4 : 2;    // d < 48
            #pragma unroll
            for (int rg = 0; rg < 4; ++rg) {
                if (rg >= rgmax) continue;
                int d0 = ot2 * 32 + rg * 8 + hi * 4;
                *(uint2*)(orow + d0) = pack4_rne(
                    O[qt][ot2][rg * 4 + 0] * inv[qt], O[qt][ot2][rg * 4 + 1] * inv[qt],
                    O[qt][ot2][rg * 4 + 2] * inv[qt], O[qt][ot2][rg * 4 + 3] * inv[qt]);
            }
        }
    }
}

extern "C" void kernel_launch(void* const* d_in, const int* in_sizes, int n_in,
                              void* d_out, int out_size, void* d_ws, size_t ws_size,
                              hipStream_t stream) {
    const float* q_x   = (const float*)d_in[0];
    const float* kv_x  = (const float*)d_in[1];
    const float* Wq    = (const float*)d_in[2];
    const float* Wkv   = (const float*)d_in[3];
    const float* Wproj = (const float*)d_in[4];
    const float* bproj = (const float*)d_in[5];
    float* out = (float*)d_out;

    unsigned short* qbf     = (unsigned short*)d_ws;  // [B,H,N,48] scaled
    unsigned short* kbf     = qbf     + 6291456;      // [B,H,M,48]
    unsigned short* vbf     = kbf     + 1572864;      // [B,H,48,M]
    unsigned short* of      = vbf     + 1572864;      // [B,N,384] bf16 attn out
    unsigned short* qx_bf   = of      + 6291456;      // [B,N,384] bf16
    unsigned short* kvx_bf  = qx_bf   + 6291456;      // [B,M,384] bf16
    unsigned short* Wq_t    = kvx_bf  + 1572864;      // [384][384]
    unsigned short* Wkv_t   = Wq_t    + 147456;       // [768][384]
    unsigned short* Wproj_t = Wkv_t   + 294912;       // [384][384]

    dim3 blk(256);

    // fused activation convert + weight transpose
    prep<<<dim3(7824), blk, 0, stream>>>(q_x, qx_bf, kv_x, kvx_bf,
                                         Wq, Wkv, Wproj, Wq_t, Wkv_t, Wproj_t);

    // fused q-proj + kv-proj (m97-style, global_load_lds staging)
    gemm_qkv<<<dim3(576), blk, 0, stream>>>(
        qx_bf, kvx_bf, Wq_t, Wkv_t, qbf, kbf, vbf);

    // attention: 512 blocks x 256 q-rows, reg-prefetch + setprio
    attn_mfma<<<dim3(32, 16), blk, 0, stream>>>(qbf, kbf, vbf, of);

    // out = q_res + of @ Wproj + bproj  (128x64 tiles, 768 blocks)
    gemm_out<<<dim3(768), blk, 0, stream>>>(of, Wproj_t, out, qbf, bproj);
}